// Round 12
// baseline (2938.575 us; speedup 1.0000x reference)
//
#include <hip/hip_runtime.h>
#include <hip/hip_bf16.h>

// HMM forward on MI355X — r8 algorithm (K=128 MX-fp8 MFMA, register-resident A,
// G-dot current-S normalization, exact telescope), re-partitioned as
// 16 WAVES x 32 ROWS (1024-thread WG) to raise waves/SIMD 2 -> 4 and saturate
// the MFMA pipe (hypothesis H: 2 waves/SIMD leave the matrix pipe ~40% idle).
// Per step: acc = A v (8 MFMA/wave, 4 chains x depth 2); gv = G[x_t]·v
// (per-wave redundant dot, overlaps MFMA); w = E ⊙ acc; v' = w/gv (fp8, u=256);
// L += log gv. Final step: exact reduction; out = L + log(Σw) − Tb·ln256.

typedef unsigned long long u64;
typedef unsigned int u32;
typedef unsigned short u16;
using f32x4 = __attribute__((ext_vector_type(4))) float;
using i32x8 = __attribute__((ext_vector_type(8))) int;

#define N_ST 512
#define VOCAB 10000
#define BATCH 64
#define T_MAX 1024

// ---------------- workspace layout (bytes) ----------------
#define WS_EB       0          // E bf16: 10000*512*2 = 10,240,000
#define WS_GB       10240000   // G bf16: 10,240,000
#define WS_A8       20480000   // 128 frags * 2048 B = 262,144
#define WS_ROWLSE   20742144   // 512 f32
#define WS_COLLSE   20744192   // 512 f32
#define WS_PINORM   20746240   // 512 f32

// ---- bf16 helpers ----
static __device__ __forceinline__ float bf16f(u16 h) {
    return __uint_as_float((u32)h << 16);
}
static __device__ __forceinline__ u16 bf16enc(float f) {
    u32 u = __float_as_uint(f);
    return (u16)((u + 0x7fffu + ((u >> 16) & 1u)) >> 16);
}

// ---- positive OCP e4m3fn decode ----
static __device__ __forceinline__ float dec8(u32 b) {
    float nrm = __uint_as_float((b << 20) + 0x3C000000u);
    float dnm = (float)b * 0x1p-9f;
    return b >= 8u ? nrm : dnm;
}

// ---- software e4m3fn encoder (fallback only) ----
static __device__ __forceinline__ u32 enc_e4m3(float f) {
    if (!(f > 0.f)) return 0u;
    unsigned u = __float_as_uint(f);
    int e = (int)((u >> 23) & 0xff) - 127;
    unsigned m = u & 0x7fffffu;
    if (e > 8 || (e == 8 && m >= 0x700000u)) return 0x7eu;
    if (e >= -6) {
        unsigned mant = m >> 20;
        unsigned rest = m & 0xfffffu;
        if (rest > 0x80000u || (rest == 0x80000u && (mant & 1u))) mant++;
        unsigned r = ((unsigned)(e + 7) << 3) + mant;
        return r > 0x7eu ? 0x7eu : r;
    }
    if (e < -10) return 0u;
    unsigned full = 0x800000u | m;
    int shift = 23 - (e + 9);
    unsigned r = full >> shift;
    unsigned rem = full & ((1u << shift) - 1u);
    unsigned half = 1u << (shift - 1);
    if (rem > half || (rem == half && (r & 1u))) r++;
    return r;
}

template <bool HI>
static __device__ __forceinline__ u32 cvtpk2(float a, float b, u32 old) {
#if __has_builtin(__builtin_amdgcn_cvt_pk_fp8_f32)
    return (u32)__builtin_amdgcn_cvt_pk_fp8_f32(a, b, (int)old, HI);
#else
    unsigned v = enc_e4m3(a) | (enc_e4m3(b) << 8);
    return HI ? ((old & 0x0000ffffu) | (v << 16)) : ((old & 0xffff0000u) | v);
#endif
}

// ---- rowLSE[n] = logsumexp_m emit[n, m] ----
__global__ __launch_bounds__(256) void k_row_lse(const float* __restrict__ emit,
                                                 float* __restrict__ rowLSE) {
    const int n = blockIdx.x;
    const float* row = emit + (size_t)n * VOCAB;
    __shared__ float redm[4], reds[4];
    const int tid = threadIdx.x, lane = tid & 63, wid = tid >> 6;

    float m = -INFINITY;
    for (int i = tid; i < VOCAB; i += 256) m = fmaxf(m, row[i]);
    #pragma unroll
    for (int o = 32; o; o >>= 1) m = fmaxf(m, __shfl_down(m, o));
    if (lane == 0) redm[wid] = m;
    __syncthreads();
    if (tid == 0) redm[0] = fmaxf(fmaxf(redm[0], redm[1]), fmaxf(redm[2], redm[3]));
    __syncthreads();
    m = redm[0];

    float s = 0.f;
    for (int i = tid; i < VOCAB; i += 256) s += __expf(row[i] - m);
    #pragma unroll
    for (int o = 32; o; o >>= 1) s += __shfl_down(s, o);
    if (lane == 0) reds[wid] = s;
    __syncthreads();
    if (tid == 0) rowLSE[n] = m + __logf(reds[0] + reds[1] + reds[2] + reds[3]);
}

// ---- Eb[m*512+n] = bf16( exp(emit[n,m] - rowLSE[n]) ) ----
__global__ __launch_bounds__(256) void k_expEmitT(const float* __restrict__ emit,
                                                  const float* __restrict__ rowLSE,
                                                  u16* __restrict__ Eb) {
    const size_t gid = (size_t)blockIdx.x * 256 + threadIdx.x;
    const int m = (int)(gid >> 9);
    const int n = (int)(gid & 511);
    Eb[gid] = bf16enc(__expf(emit[(size_t)n * VOCAB + m] - rowLSE[n]));
}

// ---- colLSE[k] = logsumexp_j trans[j, k] ----
__global__ __launch_bounds__(256) void k_col_lse(const float* __restrict__ trans,
                                                 float* __restrict__ colLSE) {
    const int k = blockIdx.x;
    const int tid = threadIdx.x, lane = tid & 63, wid = tid >> 6;
    __shared__ float redm[4], reds[4];

    float a = trans[(size_t)tid * N_ST + k];
    float b = trans[(size_t)(tid + 256) * N_ST + k];
    float m = fmaxf(a, b);
    #pragma unroll
    for (int o = 32; o; o >>= 1) m = fmaxf(m, __shfl_down(m, o));
    if (lane == 0) redm[wid] = m;
    __syncthreads();
    if (tid == 0) redm[0] = fmaxf(fmaxf(redm[0], redm[1]), fmaxf(redm[2], redm[3]));
    __syncthreads();
    m = redm[0];

    float s = __expf(a - m) + __expf(b - m);
    #pragma unroll
    for (int o = 32; o; o >>= 1) s += __shfl_down(s, o);
    if (lane == 0) reds[wid] = s;
    __syncthreads();
    if (tid == 0) colLSE[k] = m + __logf(reds[0] + reds[1] + reds[2] + reds[3]);
}

// ---- pack A (column-softmax of trans, x256) into fp8 K=128 MFMA A-fragments ----
// 16-wave layout: frag f = w*8 + ks*2 + jt  (w=wave 0..15, ks=k-slice of 128,
// jt=j-tile of 16). lane l, byte i: A[j][k], j = w*32 + jt*16 + (l&15),
//                                           k = ks*128 + (l>>4)*32 + i
__global__ __launch_bounds__(64) void k_packA_fp8(const float* __restrict__ trans,
                                                  const float* __restrict__ colLSE,
                                                  u32* __restrict__ A8) {
    const int f = blockIdx.x;        // 0..127
    const int l = threadIdx.x;       // 0..63
    const int w = f >> 3, ks = (f >> 1) & 3, jt = f & 1;
    const int j = w * 32 + jt * 16 + (l & 15);
    const int k0 = ks * 128 + (l >> 4) * 32;
    u32 dw[8];
    #pragma unroll
    for (int d = 0; d < 8; ++d) {
        float a0 = 256.0f * __expf(trans[(size_t)j * N_ST + k0 + 4 * d + 0] - colLSE[k0 + 4 * d + 0]);
        float a1 = 256.0f * __expf(trans[(size_t)j * N_ST + k0 + 4 * d + 1] - colLSE[k0 + 4 * d + 1]);
        float a2 = 256.0f * __expf(trans[(size_t)j * N_ST + k0 + 4 * d + 2] - colLSE[k0 + 4 * d + 2]);
        float a3 = 256.0f * __expf(trans[(size_t)j * N_ST + k0 + 4 * d + 3] - colLSE[k0 + 4 * d + 3]);
        u32 pk = cvtpk2<false>(a0, a1, 0u);
        dw[d] = cvtpk2<true>(a2, a3, pk);
    }
    u32* dst = A8 + (size_t)f * 512 + l * 8;
    *(uint4*)dst       = make_uint4(dw[0], dw[1], dw[2], dw[3]);
    *(uint4*)(dst + 4) = make_uint4(dw[4], dw[5], dw[6], dw[7]);
}

// ---- pinorm[j] = softmax(priors)[j] ----
__global__ __launch_bounds__(512) void k_pinorm(const float* __restrict__ priors,
                                                float* __restrict__ pinorm) {
    const int j = threadIdx.x, lane = j & 63, wid = j >> 6;
    __shared__ float redm[8], reds[8];
    float v = priors[j];

    float m = v;
    #pragma unroll
    for (int o = 32; o; o >>= 1) m = fmaxf(m, __shfl_down(m, o));
    if (lane == 0) redm[wid] = m;
    __syncthreads();
    if (j == 0) {
        float r = redm[0];
        for (int i = 1; i < 8; ++i) r = fmaxf(r, redm[i]);
        redm[0] = r;
    }
    __syncthreads();
    m = redm[0];

    float s = __expf(v - m);
    #pragma unroll
    for (int o = 32; o; o >>= 1) s += __shfl_down(s, o);
    if (lane == 0) reds[wid] = s;
    __syncthreads();
    if (j == 0) {
        float r = 0.f;
        for (int i = 0; i < 8; ++i) r += reds[i];
        reds[0] = r;
    }
    __syncthreads();
    pinorm[j] = __expf(v - m) / reds[0];
}

// ---- G[m][k] = sum_j E[m][j] * A[j][k] (true A) ----
__global__ __launch_bounds__(256) void k_G(const u16* __restrict__ Eb,
                                           const float* __restrict__ trans,
                                           const float* __restrict__ colLSE,
                                           u16* __restrict__ Gb) {
    __shared__ float Es[16][512];
    const int m0 = blockIdx.x * 16;
    const int tid = threadIdx.x;
    for (int idx = tid; idx < 16 * 512; idx += 256)
        Es[idx >> 9][idx & 511] = bf16f(Eb[(size_t)(m0 + (idx >> 9)) * 512 + (idx & 511)]);
    __syncthreads();

    const int k0 = tid, k1 = tid + 256;
    const float c0 = colLSE[k0], c1 = colLSE[k1];
    float acc0[16], acc1[16];
    #pragma unroll
    for (int mi = 0; mi < 16; ++mi) { acc0[mi] = 0.f; acc1[mi] = 0.f; }

    for (int j = 0; j < 512; ++j) {
        float a0 = __expf(trans[(size_t)j * N_ST + k0] - c0);
        float a1 = __expf(trans[(size_t)j * N_ST + k1] - c1);
        #pragma unroll
        for (int mi = 0; mi < 16; ++mi) {
            float e = Es[mi][j];
            acc0[mi] = fmaf(e, a0, acc0[mi]);
            acc1[mi] = fmaf(e, a1, acc1[mi]);
        }
    }
    #pragma unroll
    for (int mi = 0; mi < 16; ++mi) {
        Gb[(size_t)(m0 + mi) * N_ST + k0] = bf16enc(acc0[mi]);
        Gb[(size_t)(m0 + mi) * N_ST + k1] = bf16enc(acc1[mi]);
    }
}

#define UNIT_SCALES 0x7f7f7f7f   // 4x e8m0 "1.0"
#define LN256 5.545177444479562f

// raw workgroup barrier: drain LDS only (vmem prefetch stays in flight)
#define WG_BARRIER()                                        \
  {                                                         \
    asm volatile("s_waitcnt lgkmcnt(0)" ::: "memory");      \
    __builtin_amdgcn_s_barrier();                           \
    asm volatile("" ::: "memory");                          \
  }

// one HMM step; EU = current E regs (2), GU = current G reg,
// EP/GP = prefetch targets.
#define STEP_BODY(EU, GU, EP, GP)                                               \
  {                                                                             \
    const int xpre = xnext;                                                     \
    GP = *(const uint4*)((const char*)Gb + ((size_t)xpre << 10) + (l << 4));    \
    _Pragma("unroll")                                                           \
    for (int jt = 0; jt < 2; ++jt)                                              \
      EP[jt] = *(const u64*)(Eb + (size_t)xpre * N_ST + wbase + jt * 16 + rbase); \
    xnext = xb[(t + 2 <= Tf) ? (t + 2) : Tf];                                   \
    const u64 vown = vq[p][l];                                                  \
    const char* vbase = (const char*)&vq[p][0];                                 \
    i32x8 bq[4];                                                                \
    _Pragma("unroll")                                                           \
    for (int ks = 0; ks < 4; ++ks)                                              \
      bq[ks] = *(const i32x8*)(vbase + ks * 128 + grp * 32);                    \
    f32x4 aA0={0,0,0,0}, aA1={0,0,0,0}, aB0={0,0,0,0}, aB1={0,0,0,0};           \
    _Pragma("unroll")                                                           \
    for (int ks = 0; ks < 2; ++ks) {                                            \
      aA0 = __builtin_amdgcn_mfma_scale_f32_16x16x128_f8f6f4(                   \
                af[ks * 2 + 0], bq[ks], aA0, 0, 0, 0, UNIT_SCALES, 0, UNIT_SCALES); \
      aA1 = __builtin_amdgcn_mfma_scale_f32_16x16x128_f8f6f4(                   \
                af[ks * 2 + 1], bq[ks], aA1, 0, 0, 0, UNIT_SCALES, 0, UNIT_SCALES); \
    }                                                                           \
    _Pragma("unroll")                                                           \
    for (int ks = 2; ks < 4; ++ks) {                                            \
      aB0 = __builtin_amdgcn_mfma_scale_f32_16x16x128_f8f6f4(                   \
                af[ks * 2 + 0], bq[ks], aB0, 0, 0, 0, UNIT_SCALES, 0, UNIT_SCALES); \
      aB1 = __builtin_amdgcn_mfma_scale_f32_16x16x128_f8f6f4(                   \
                af[ks * 2 + 1], bq[ks], aB1, 0, 0, 0, UNIT_SCALES, 0, UNIT_SCALES); \
    }                                                                           \
    float gv = 0.f;                                                             \
    {                                                                           \
      const u32 gw[4] = {GU.x, GU.y, GU.z, GU.w};                               \
      _Pragma("unroll")                                                         \
      for (int i = 0; i < 4; ++i) {                                             \
        float g0 = bf16f((u16)(gw[i] & 0xffffu));                               \
        float g1 = bf16f((u16)(gw[i] >> 16));                                   \
        float v0 = dec8((u32)(vown >> (16 * i)) & 0xffu);                       \
        float v1 = dec8((u32)(vown >> (16 * i + 8)) & 0xffu);                   \
        gv = fmaf(g0, v0, gv);                                                  \
        gv = fmaf(g1, v1, gv);                                                  \
      }                                                                         \
      _Pragma("unroll")                                                         \
      for (int o = 1; o <= 32; o <<= 1) gv += __shfl_xor(gv, o);                \
    }                                                                           \
    float wv2[8];                                                               \
    _Pragma("unroll")                                                           \
    for (int r = 0; r < 4; ++r) {                                               \
      wv2[0 + r] = bf16f((u16)(EU[0] >> (16 * r))) * (aA0[r] + aB0[r]);         \
      wv2[4 + r] = bf16f((u16)(EU[1] >> (16 * r))) * (aA1[r] + aB1[r]);         \
    }                                                                           \
    if (t == Tf) {                                                              \
      float s2 = 0.f;                                                           \
      _Pragma("unroll")                                                         \
      for (int i = 0; i < 8; ++i) s2 += wv2[i];                                 \
      s2 += __shfl_xor(s2, 16);                                                 \
      s2 += __shfl_xor(s2, 32);                                                 \
      if (l == 0) redF[wid] = s2;                                               \
      __syncthreads();                                                          \
      float Se = 0.f;                                                           \
      _Pragma("unroll")                                                         \
      for (int i = 0; i < 16; ++i) Se += redF[i];                               \
      if (tid == 0) out[b] = L + __logf(Se) - (float)Tb * LN256;                \
    } else {                                                                    \
      L += __logf(gv);                                                          \
      const float sc = 1.0f / gv;                                               \
      if ((l & 15) == 0) {                                                      \
        u32* vw = (u32*)&vq[p ^ 1][0];                                          \
        _Pragma("unroll")                                                       \
        for (int jt = 0; jt < 2; ++jt) {                                        \
          u32 pk = cvtpk2<false>(wv2[jt * 4 + 0] * sc, wv2[jt * 4 + 1] * sc, 0u); \
          pk = cvtpk2<true>(wv2[jt * 4 + 2] * sc, wv2[jt * 4 + 3] * sc, pk);    \
          vw[wid * 8 + jt * 4 + grp] = pk;                                      \
        }                                                                       \
      }                                                                         \
      WG_BARRIER();                                                             \
      p ^= 1;                                                                   \
    }                                                                           \
  }

// ---- main: one WG per chain; 16 waves x 32 states; A resident (K=128 frags) ----
__global__ __launch_bounds__(1024, 1) void hmm_main(const int* __restrict__ x,
                                                    const int* __restrict__ T,
                                                    const u16* __restrict__ Eb,
                                                    const u32* __restrict__ A8,
                                                    const u16* __restrict__ Gb,
                                                    const float* __restrict__ pinorm,
                                                    float* __restrict__ out) {
    __shared__ __align__(64) u64 vq[2][64];
    __shared__ __align__(16) float redF[16];
    const int b = blockIdx.x;
    const int tid = threadIdx.x;
    const int l = tid & 63;
    const int wid = tid >> 6;        // 0..15
    const int grp = l >> 4;
    const int wbase = wid * 32;
    const int rbase = grp * 4;

    int Tb = T[b];
    Tb = Tb < 1 ? 1 : (Tb > T_MAX ? T_MAX : Tb);
    const int* xb = x + (size_t)b * T_MAX;

    // resident A fragments: 8 x 32 B per lane (64 regs)
    i32x8 af[8];
    {
        const u32* ap = A8 + (size_t)wid * 8 * 512 + l * 8;
        #pragma unroll
        for (int i = 0; i < 8; ++i)
            af[i] = *(const i32x8*)(ap + (size_t)i * 512);
    }

    // prefetch E/G for t=1 immediately (x known upfront; harmless if Tb==1)
    const int x0 = xb[0];
    const int x1 = xb[1];
    u64 eA[2], eB[2];
    uint4 gA, gB;
    gA = *(const uint4*)((const char*)Gb + ((size_t)x1 << 10) + (l << 4));
    #pragma unroll
    for (int jt = 0; jt < 2; ++jt)
        eA[jt] = *(const u64*)(Eb + (size_t)x1 * N_ST + wbase + jt * 16 + rbase);

    // ---- t = 0 ----
    float wv[8];
    float s = 0.f;
    #pragma unroll
    for (int jt = 0; jt < 2; ++jt) {
        u64 eraw = *(const u64*)(Eb + (size_t)x0 * N_ST + wbase + jt * 16 + rbase);
        #pragma unroll
        for (int r = 0; r < 4; ++r) {
            const int j = wbase + jt * 16 + rbase + r;
            float e = bf16f((u16)(eraw >> (16 * r)));
            float t0 = e * pinorm[j];
            wv[jt * 4 + r] = t0;
            s += t0;
        }
    }
    s += __shfl_xor(s, 16);
    s += __shfl_xor(s, 32);
    if (l == 0) redF[wid] = s;
    __syncthreads();
    float S0 = 0.f;
    #pragma unroll
    for (int i = 0; i < 16; ++i) S0 += redF[i];
    float L = __logf(S0);
    if (Tb == 1) {
        if (tid == 0) out[b] = L;
        return;
    }
    __syncthreads();                 // all waves done reading redF
    {
        const float sc = 256.0f / S0;
        if ((l & 15) == 0) {
            u32* vw = (u32*)&vq[0][0];
            #pragma unroll
            for (int jt = 0; jt < 2; ++jt) {
                u32 pk = cvtpk2<false>(wv[jt * 4 + 0] * sc, wv[jt * 4 + 1] * sc, 0u);
                pk = cvtpk2<true>(wv[jt * 4 + 2] * sc, wv[jt * 4 + 3] * sc, pk);
                vw[wid * 8 + jt * 4 + grp] = pk;
            }
        }
    }
    __syncthreads();

    // ---- t = 1 .. Tb-1 (unroll-2 with register E/G double-buffer) ----
    const int Tf = Tb - 1;
    int p = 0;
    int xnext = xb[(2 <= Tf) ? 2 : Tf];
    for (int t = 1;;) {
        STEP_BODY(eA, gA, eB, gB)
        if (t == Tf) break;
        ++t;
        STEP_BODY(eB, gB, eA, gA)
        if (t == Tf) break;
        ++t;
    }
}

extern "C" void kernel_launch(void* const* d_in, const int* in_sizes, int n_in,
                              void* d_out, int out_size, void* d_ws, size_t ws_size,
                              hipStream_t stream) {
    const int*   x      = (const int*)d_in[0];     // (64, 1024)
    const int*   T      = (const int*)d_in[1];     // (64,)
    const float* priors = (const float*)d_in[2];   // (512,)
    const float* trans  = (const float*)d_in[3];   // (512, 512)
    const float* emit   = (const float*)d_in[4];   // (512, 10000)
    float* out = (float*)d_out;                    // (64, 1)

    char* ws = (char*)d_ws;
    u16*   Eb     = (u16*)(ws + WS_EB);
    u16*   Gb     = (u16*)(ws + WS_GB);
    u32*   A8     = (u32*)(ws + WS_A8);
    float* rowLSE = (float*)(ws + WS_ROWLSE);
    float* colLSE = (float*)(ws + WS_COLLSE);
    float* pinorm = (float*)(ws + WS_PINORM);

    k_row_lse<<<N_ST, 256, 0, stream>>>(emit, rowLSE);
    k_expEmitT<<<(VOCAB * N_ST) / 256, 256, 0, stream>>>(emit, rowLSE, Eb);
    k_col_lse<<<N_ST, 256, 0, stream>>>(trans, colLSE);
    k_packA_fp8<<<128, 64, 0, stream>>>(trans, colLSE, A8);
    k_pinorm<<<1, 512, 0, stream>>>(priors, pinorm);
    k_G<<<VOCAB / 16, 256, 0, stream>>>(Eb, trans, colLSE, Gb);

    hmm_main<<<BATCH, 1024, 0, stream>>>(x, T, Eb, A8, Gb, pinorm, out);
}

// Round 13
// 1278.721 us; speedup vs baseline: 2.2981x; 2.2981x over previous
//
#include <hip/hip_runtime.h>
#include <hip/hip_bf16.h>

// HMM forward on MI355X — K=128 MX-fp8 MFMA (unit scales), register-resident A,
// 1-step register prefetch of E/G rows, G-dot current-S normalization (exact
// telescope), RAW s_barrier (lgkm-only drain). hmm_main identical to the
// proven r8 kernel (1147 us, absmax 0.5). This round: precompute trimmed —
// k_expEmitT tiled-transpose (coalesced), k_G b128 Es reads (4 j's per read).

typedef unsigned long long u64;
typedef unsigned int u32;
typedef unsigned short u16;
using f32x4 = __attribute__((ext_vector_type(4))) float;
using i32x8 = __attribute__((ext_vector_type(8))) int;

#define N_ST 512
#define VOCAB 10000
#define BATCH 64
#define T_MAX 1024

// ---------------- workspace layout (bytes) ----------------
#define WS_EB       0          // E bf16: 10000*512*2 = 10,240,000
#define WS_GB       10240000   // G bf16: 10,240,000
#define WS_A8       20480000   // 128 frags * 2048 B = 262,144
#define WS_ROWLSE   20742144   // 512 f32
#define WS_COLLSE   20744192   // 512 f32
#define WS_PINORM   20746240   // 512 f32

// ---- bf16 helpers ----
static __device__ __forceinline__ float bf16f(u16 h) {
    return __uint_as_float((u32)h << 16);
}
static __device__ __forceinline__ u16 bf16enc(float f) {
    u32 u = __float_as_uint(f);
    return (u16)((u + 0x7fffu + ((u >> 16) & 1u)) >> 16);
}

// ---- positive OCP e4m3fn decode ----
static __device__ __forceinline__ float dec8(u32 b) {
    float nrm = __uint_as_float((b << 20) + 0x3C000000u);
    float dnm = (float)b * 0x1p-9f;
    return b >= 8u ? nrm : dnm;
}

// ---- software e4m3fn encoder (fallback only) ----
static __device__ __forceinline__ u32 enc_e4m3(float f) {
    if (!(f > 0.f)) return 0u;
    unsigned u = __float_as_uint(f);
    int e = (int)((u >> 23) & 0xff) - 127;
    unsigned m = u & 0x7fffffu;
    if (e > 8 || (e == 8 && m >= 0x700000u)) return 0x7eu;
    if (e >= -6) {
        unsigned mant = m >> 20;
        unsigned rest = m & 0xfffffu;
        if (rest > 0x80000u || (rest == 0x80000u && (mant & 1u))) mant++;
        unsigned r = ((unsigned)(e + 7) << 3) + mant;
        return r > 0x7eu ? 0x7eu : r;
    }
    if (e < -10) return 0u;
    unsigned full = 0x800000u | m;
    int shift = 23 - (e + 9);
    unsigned r = full >> shift;
    unsigned rem = full & ((1u << shift) - 1u);
    unsigned half = 1u << (shift - 1);
    if (rem > half || (rem == half && (r & 1u))) r++;
    return r;
}

template <bool HI>
static __device__ __forceinline__ u32 cvtpk2(float a, float b, u32 old) {
#if __has_builtin(__builtin_amdgcn_cvt_pk_fp8_f32)
    return (u32)__builtin_amdgcn_cvt_pk_fp8_f32(a, b, (int)old, HI);
#else
    unsigned v = enc_e4m3(a) | (enc_e4m3(b) << 8);
    return HI ? ((old & 0x0000ffffu) | (v << 16)) : ((old & 0xffff0000u) | v);
#endif
}

// ---- rowLSE[n] = logsumexp_m emit[n, m] ----
__global__ __launch_bounds__(256) void k_row_lse(const float* __restrict__ emit,
                                                 float* __restrict__ rowLSE) {
    const int n = blockIdx.x;
    const float* row = emit + (size_t)n * VOCAB;
    __shared__ float redm[4], reds[4];
    const int tid = threadIdx.x, lane = tid & 63, wid = tid >> 6;

    float m = -INFINITY;
    for (int i = tid; i < VOCAB; i += 256) m = fmaxf(m, row[i]);
    #pragma unroll
    for (int o = 32; o; o >>= 1) m = fmaxf(m, __shfl_down(m, o));
    if (lane == 0) redm[wid] = m;
    __syncthreads();
    if (tid == 0) redm[0] = fmaxf(fmaxf(redm[0], redm[1]), fmaxf(redm[2], redm[3]));
    __syncthreads();
    m = redm[0];

    float s = 0.f;
    for (int i = tid; i < VOCAB; i += 256) s += __expf(row[i] - m);
    #pragma unroll
    for (int o = 32; o; o >>= 1) s += __shfl_down(s, o);
    if (lane == 0) reds[wid] = s;
    __syncthreads();
    if (tid == 0) rowLSE[n] = m + __logf(reds[0] + reds[1] + reds[2] + reds[3]);
}

// ---- Eb[m*512+n] = bf16( exp(emit[n,m] - rowLSE[n]) ), tiled transpose ----
// 64x64 tile in LDS (+1 pad): coalesced read along m, coalesced write along n.
__global__ __launch_bounds__(256) void k_expEmitT(const float* __restrict__ emit,
                                                  const float* __restrict__ rowLSE,
                                                  u16* __restrict__ Eb) {
    __shared__ float tile[64][65];
    const int m0 = blockIdx.x * 64;     // vocab tile (157 tiles, last partial)
    const int n0 = blockIdx.y * 64;     // state tile (8 tiles)
    const int tid = threadIdx.x;

    #pragma unroll
    for (int it = 0; it < 16; ++it) {
        const int idx = it * 256 + tid;
        const int mm = idx & 63, nn = idx >> 6;
        const int m = m0 + mm;
        tile[nn][mm] = (m < VOCAB) ? emit[(size_t)(n0 + nn) * VOCAB + m] : 0.f;
    }
    __syncthreads();
    #pragma unroll
    for (int it = 0; it < 16; ++it) {
        const int idx = it * 256 + tid;
        const int nn = idx & 63, mm = idx >> 6;
        const int m = m0 + mm;
        if (m < VOCAB)
            Eb[(size_t)m * N_ST + n0 + nn] =
                bf16enc(__expf(tile[nn][mm] - rowLSE[n0 + nn]));
    }
}

// ---- colLSE[k] = logsumexp_j trans[j, k] ----
__global__ __launch_bounds__(256) void k_col_lse(const float* __restrict__ trans,
                                                 float* __restrict__ colLSE) {
    const int k = blockIdx.x;
    const int tid = threadIdx.x, lane = tid & 63, wid = tid >> 6;
    __shared__ float redm[4], reds[4];

    float a = trans[(size_t)tid * N_ST + k];
    float b = trans[(size_t)(tid + 256) * N_ST + k];
    float m = fmaxf(a, b);
    #pragma unroll
    for (int o = 32; o; o >>= 1) m = fmaxf(m, __shfl_down(m, o));
    if (lane == 0) redm[wid] = m;
    __syncthreads();
    if (tid == 0) redm[0] = fmaxf(fmaxf(redm[0], redm[1]), fmaxf(redm[2], redm[3]));
    __syncthreads();
    m = redm[0];

    float s = __expf(a - m) + __expf(b - m);
    #pragma unroll
    for (int o = 32; o; o >>= 1) s += __shfl_down(s, o);
    if (lane == 0) reds[wid] = s;
    __syncthreads();
    if (tid == 0) colLSE[k] = m + __logf(reds[0] + reds[1] + reds[2] + reds[3]);
}

// ---- pack A (column-softmax of trans, x256) into fp8 K=128 MFMA A-fragments ----
__global__ __launch_bounds__(64) void k_packA_fp8(const float* __restrict__ trans,
                                                  const float* __restrict__ colLSE,
                                                  u32* __restrict__ A8) {
    const int f = blockIdx.x;        // 0..127
    const int l = threadIdx.x;       // 0..63
    const int w = f >> 4, ks = (f >> 2) & 3, jt = f & 3;
    const int j = w * 64 + jt * 16 + (l & 15);
    const int k0 = ks * 128 + (l >> 4) * 32;
    u32 dw[8];
    #pragma unroll
    for (int d = 0; d < 8; ++d) {
        float a0 = 256.0f * __expf(trans[(size_t)j * N_ST + k0 + 4 * d + 0] - colLSE[k0 + 4 * d + 0]);
        float a1 = 256.0f * __expf(trans[(size_t)j * N_ST + k0 + 4 * d + 1] - colLSE[k0 + 4 * d + 1]);
        float a2 = 256.0f * __expf(trans[(size_t)j * N_ST + k0 + 4 * d + 2] - colLSE[k0 + 4 * d + 2]);
        float a3 = 256.0f * __expf(trans[(size_t)j * N_ST + k0 + 4 * d + 3] - colLSE[k0 + 4 * d + 3]);
        u32 pk = cvtpk2<false>(a0, a1, 0u);
        dw[d] = cvtpk2<true>(a2, a3, pk);
    }
    u32* dst = A8 + (size_t)f * 512 + l * 8;
    *(uint4*)dst       = make_uint4(dw[0], dw[1], dw[2], dw[3]);
    *(uint4*)(dst + 4) = make_uint4(dw[4], dw[5], dw[6], dw[7]);
}

// ---- pinorm[j] = softmax(priors)[j] ----
__global__ __launch_bounds__(512) void k_pinorm(const float* __restrict__ priors,
                                                float* __restrict__ pinorm) {
    const int j = threadIdx.x, lane = j & 63, wid = j >> 6;
    __shared__ float redm[8], reds[8];
    float v = priors[j];

    float m = v;
    #pragma unroll
    for (int o = 32; o; o >>= 1) m = fmaxf(m, __shfl_down(m, o));
    if (lane == 0) redm[wid] = m;
    __syncthreads();
    if (j == 0) {
        float r = redm[0];
        for (int i = 1; i < 8; ++i) r = fmaxf(r, redm[i]);
        redm[0] = r;
    }
    __syncthreads();
    m = redm[0];

    float s = __expf(v - m);
    #pragma unroll
    for (int o = 32; o; o >>= 1) s += __shfl_down(s, o);
    if (lane == 0) reds[wid] = s;
    __syncthreads();
    if (j == 0) {
        float r = 0.f;
        for (int i = 0; i < 8; ++i) r += reds[i];
        reds[0] = r;
    }
    __syncthreads();
    pinorm[j] = __expf(v - m) / reds[0];
}

// ---- G[m][k] = sum_j E[m][j] * A[j][k] (true A); b128 Es reads, 4 j per iter ----
__global__ __launch_bounds__(256) void k_G(const u16* __restrict__ Eb,
                                           const float* __restrict__ trans,
                                           const float* __restrict__ colLSE,
                                           u16* __restrict__ Gb) {
    __shared__ float Es[16][512];
    const int m0 = blockIdx.x * 16;
    const int tid = threadIdx.x;
    for (int idx = tid; idx < 16 * 512; idx += 256)
        Es[idx >> 9][idx & 511] = bf16f(Eb[(size_t)(m0 + (idx >> 9)) * 512 + (idx & 511)]);
    __syncthreads();

    const int k0 = tid, k1 = tid + 256;
    const float c0 = colLSE[k0], c1 = colLSE[k1];
    float acc0[16], acc1[16];
    #pragma unroll
    for (int mi = 0; mi < 16; ++mi) { acc0[mi] = 0.f; acc1[mi] = 0.f; }

    for (int j4 = 0; j4 < 128; ++j4) {
        float a0[4], a1[4];
        #pragma unroll
        for (int d = 0; d < 4; ++d) {
            a0[d] = __expf(trans[(size_t)(4 * j4 + d) * N_ST + k0] - c0);
            a1[d] = __expf(trans[(size_t)(4 * j4 + d) * N_ST + k1] - c1);
        }
        #pragma unroll
        for (int mi = 0; mi < 16; ++mi) {
            const f32x4 e = *(const f32x4*)&Es[mi][4 * j4];
            acc0[mi] = fmaf(e[0], a0[0], fmaf(e[1], a0[1],
                       fmaf(e[2], a0[2], fmaf(e[3], a0[3], acc0[mi]))));
            acc1[mi] = fmaf(e[0], a1[0], fmaf(e[1], a1[1],
                       fmaf(e[2], a1[2], fmaf(e[3], a1[3], acc1[mi]))));
        }
    }
    #pragma unroll
    for (int mi = 0; mi < 16; ++mi) {
        Gb[(size_t)(m0 + mi) * N_ST + k0] = bf16enc(acc0[mi]);
        Gb[(size_t)(m0 + mi) * N_ST + k1] = bf16enc(acc1[mi]);
    }
}

#define UNIT_SCALES 0x7f7f7f7f   // 4x e8m0 "1.0"
#define LN256 5.545177444479562f

// raw workgroup barrier: drain LDS only (vmem prefetch stays in flight)
#define WG_BARRIER()                                        \
  {                                                         \
    asm volatile("s_waitcnt lgkmcnt(0)" ::: "memory");      \
    __builtin_amdgcn_s_barrier();                           \
    asm volatile("" ::: "memory");                          \
  }

// one HMM step; EU/GU = current-step E/G regs, EP/GP = prefetch targets
#define STEP_BODY(EU, GU, EP, GP)                                               \
  {                                                                             \
    const int xpre = xnext;                                                     \
    GP = *(const uint4*)((const char*)Gb + ((size_t)xpre << 10) + (l << 4));    \
    _Pragma("unroll")                                                           \
    for (int jt = 0; jt < 4; ++jt)                                              \
      EP[jt] = *(const u64*)(Eb + (size_t)xpre * N_ST + wbase + jt * 16 + rbase); \
    xnext = xb[(t + 2 <= Tf) ? (t + 2) : Tf];                                   \
    const u64 vown = vq[p][l];                                                  \
    const u32* vbase = (const u32*)&vq[p][0];                                   \
    i32x8 bq[4];                                                                \
    _Pragma("unroll")                                                           \
    for (int ks = 0; ks < 4; ++ks) {                                            \
      const uint4 b0 = *(const uint4*)(vbase + ks * 32 + grp * 8);              \
      const uint4 b1 = *(const uint4*)(vbase + ks * 32 + grp * 8 + 4);          \
      bq[ks] = i32x8{(int)b0.x, (int)b0.y, (int)b0.z, (int)b0.w,                \
                     (int)b1.x, (int)b1.y, (int)b1.z, (int)b1.w};               \
    }                                                                           \
    f32x4 aA0={0,0,0,0}, aA1={0,0,0,0}, aA2={0,0,0,0}, aA3={0,0,0,0};           \
    f32x4 aB0={0,0,0,0}, aB1={0,0,0,0}, aB2={0,0,0,0}, aB3={0,0,0,0};           \
    _Pragma("unroll")                                                           \
    for (int kk = 0; kk < 2; ++kk) {                                            \
      const int ksA = kk * 2, ksB = kk * 2 + 1;                                 \
      aA0 = __builtin_amdgcn_mfma_scale_f32_16x16x128_f8f6f4(                   \
                af[ksA * 4 + 0], bq[ksA], aA0, 0, 0, 0, UNIT_SCALES, 0, UNIT_SCALES); \
      aB0 = __builtin_amdgcn_mfma_scale_f32_16x16x128_f8f6f4(                   \
                af[ksB * 4 + 0], bq[ksB], aB0, 0, 0, 0, UNIT_SCALES, 0, UNIT_SCALES); \
      aA1 = __builtin_amdgcn_mfma_scale_f32_16x16x128_f8f6f4(                   \
                af[ksA * 4 + 1], bq[ksA], aA1, 0, 0, 0, UNIT_SCALES, 0, UNIT_SCALES); \
      aB1 = __builtin_amdgcn_mfma_scale_f32_16x16x128_f8f6f4(                   \
                af[ksB * 4 + 1], bq[ksB], aB1, 0, 0, 0, UNIT_SCALES, 0, UNIT_SCALES); \
      aA2 = __builtin_amdgcn_mfma_scale_f32_16x16x128_f8f6f4(                   \
                af[ksA * 4 + 2], bq[ksA], aA2, 0, 0, 0, UNIT_SCALES, 0, UNIT_SCALES); \
      aB2 = __builtin_amdgcn_mfma_scale_f32_16x16x128_f8f6f4(                   \
                af[ksB * 4 + 2], bq[ksB], aB2, 0, 0, 0, UNIT_SCALES, 0, UNIT_SCALES); \
      aA3 = __builtin_amdgcn_mfma_scale_f32_16x16x128_f8f6f4(                   \
                af[ksA * 4 + 3], bq[ksA], aA3, 0, 0, 0, UNIT_SCALES, 0, UNIT_SCALES); \
      aB3 = __builtin_amdgcn_mfma_scale_f32_16x16x128_f8f6f4(                   \
                af[ksB * 4 + 3], bq[ksB], aB3, 0, 0, 0, UNIT_SCALES, 0, UNIT_SCALES); \
    }                                                                           \
    float gv = 0.f;                                                             \
    {                                                                           \
      const u32 gw[4] = {GU.x, GU.y, GU.z, GU.w};                               \
      _Pragma("unroll")                                                         \
      for (int i = 0; i < 4; ++i) {                                             \
        float g0 = bf16f((u16)(gw[i] & 0xffffu));                               \
        float g1 = bf16f((u16)(gw[i] >> 16));                                   \
        float v0 = dec8((u32)(vown >> (16 * i)) & 0xffu);                       \
        float v1 = dec8((u32)(vown >> (16 * i + 8)) & 0xffu);                   \
        gv = fmaf(g0, v0, gv);                                                  \
        gv = fmaf(g1, v1, gv);                                                  \
      }                                                                         \
      _Pragma("unroll")                                                         \
      for (int o = 1; o <= 32; o <<= 1) gv += __shfl_xor(gv, o);                \
    }                                                                           \
    float wv2[16];                                                              \
    _Pragma("unroll")                                                           \
    for (int r = 0; r < 4; ++r) {                                               \
      wv2[0 + r]  = bf16f((u16)(EU[0] >> (16 * r))) * (aA0[r] + aB0[r]);        \
      wv2[4 + r]  = bf16f((u16)(EU[1] >> (16 * r))) * (aA1[r] + aB1[r]);        \
      wv2[8 + r]  = bf16f((u16)(EU[2] >> (16 * r))) * (aA2[r] + aB2[r]);        \
      wv2[12 + r] = bf16f((u16)(EU[3] >> (16 * r))) * (aA3[r] + aB3[r]);        \
    }                                                                           \
    if (t == Tf) {                                                              \
      float s2 = 0.f;                                                           \
      _Pragma("unroll")                                                         \
      for (int i = 0; i < 16; ++i) s2 += wv2[i];                                \
      s2 += __shfl_xor(s2, 16);                                                 \
      s2 += __shfl_xor(s2, 32);                                                 \
      if (l == 0) red[wid] = s2;                                                \
      __syncthreads();                                                          \
      const float Se = red[0] + red[1] + red[2] + red[3] +                      \
                       red[4] + red[5] + red[6] + red[7];                       \
      if (tid == 0) out[b] = L + __logf(Se) - (float)Tb * LN256;                \
    } else {                                                                    \
      L += __logf(gv);                                                          \
      const float sc = 1.0f / gv;                                               \
      if ((l & 15) == 0) {                                                      \
        u32* vw = (u32*)&vq[p ^ 1][0];                                          \
        _Pragma("unroll")                                                       \
        for (int jt = 0; jt < 4; ++jt) {                                        \
          u32 pk = cvtpk2<false>(wv2[jt * 4 + 0] * sc, wv2[jt * 4 + 1] * sc, 0u); \
          pk = cvtpk2<true>(wv2[jt * 4 + 2] * sc, wv2[jt * 4 + 3] * sc, pk);    \
          vw[(wbase >> 2) + jt * 4 + grp] = pk;                                 \
        }                                                                       \
      }                                                                         \
      WG_BARRIER();                                                             \
      p ^= 1;                                                                   \
    }                                                                           \
  }

// ---- main: one WG per chain; 8 waves x 64 states; A resident (K=128 frags) ----
__global__ __launch_bounds__(512, 2) void hmm_main(const int* __restrict__ x,
                                                   const int* __restrict__ T,
                                                   const u16* __restrict__ Eb,
                                                   const u32* __restrict__ A8,
                                                   const u16* __restrict__ Gb,
                                                   const float* __restrict__ pinorm,
                                                   float* __restrict__ out) {
    __shared__ u64 vq[2][64];
    __shared__ float red[8];
    const int b = blockIdx.x;
    const int tid = threadIdx.x;
    const int l = tid & 63;
    const int wid = tid >> 6;
    const int grp = l >> 4;
    const int wbase = wid * 64;
    const int rbase = grp * 4;

    int Tb = T[b];
    Tb = Tb < 1 ? 1 : (Tb > T_MAX ? T_MAX : Tb);
    const int* xb = x + (size_t)b * T_MAX;

    // resident A fragments: 16 x 32 B per lane (128 VGPRs)
    i32x8 af[16];
    {
        const u32* ap = A8 + (size_t)wid * 16 * 512 + l * 8;
        #pragma unroll
        for (int i = 0; i < 16; ++i) {
            uint4 lo = *(const uint4*)(ap + (size_t)i * 512);
            uint4 hi = *(const uint4*)(ap + (size_t)i * 512 + 4);
            af[i] = i32x8{(int)lo.x, (int)lo.y, (int)lo.z, (int)lo.w,
                          (int)hi.x, (int)hi.y, (int)hi.z, (int)hi.w};
        }
    }

    // prefetch E/G for t=1 immediately (x known upfront; harmless if Tb==1)
    const int x0 = xb[0];
    const int x1 = xb[1];
    u64 eA[4], eB[4];
    uint4 gA, gB;
    gA = *(const uint4*)((const char*)Gb + ((size_t)x1 << 10) + (l << 4));
    #pragma unroll
    for (int jt = 0; jt < 4; ++jt)
        eA[jt] = *(const u64*)(Eb + (size_t)x1 * N_ST + wbase + jt * 16 + rbase);

    // ---- t = 0 ----
    float wv[16];
    float s = 0.f;
    #pragma unroll
    for (int jt = 0; jt < 4; ++jt) {
        u64 eraw = *(const u64*)(Eb + (size_t)x0 * N_ST + wbase + jt * 16 + rbase);
        #pragma unroll
        for (int r = 0; r < 4; ++r) {
            const int j = wbase + jt * 16 + rbase + r;
            float e = bf16f((u16)(eraw >> (16 * r)));
            float t0 = e * pinorm[j];
            wv[jt * 4 + r] = t0;
            s += t0;
        }
    }
    s += __shfl_xor(s, 16);
    s += __shfl_xor(s, 32);
    if (l == 0) red[wid] = s;
    __syncthreads();
    float S0 = red[0] + red[1] + red[2] + red[3] + red[4] + red[5] + red[6] + red[7];
    float L = __logf(S0);
    if (Tb == 1) {
        if (tid == 0) out[b] = L;
        return;
    }
    __syncthreads();
    {
        const float sc = 256.0f / S0;
        if ((l & 15) == 0) {
            u32* vw = (u32*)&vq[0][0];
            #pragma unroll
            for (int jt = 0; jt < 4; ++jt) {
                u32 pk = cvtpk2<false>(wv[jt * 4 + 0] * sc, wv[jt * 4 + 1] * sc, 0u);
                pk = cvtpk2<true>(wv[jt * 4 + 2] * sc, wv[jt * 4 + 3] * sc, pk);
                vw[(wbase >> 2) + jt * 4 + grp] = pk;
            }
        }
    }
    __syncthreads();

    // ---- t = 1 .. Tb-1 (unroll-2 with register E/G double-buffer) ----
    const int Tf = Tb - 1;
    int p = 0;
    int xnext = xb[(2 <= Tf) ? 2 : Tf];
    for (int t = 1;;) {
        STEP_BODY(eA, gA, eB, gB)
        if (t == Tf) break;
        ++t;
        STEP_BODY(eB, gB, eA, gA)
        if (t == Tf) break;
        ++t;
    }
}

extern "C" void kernel_launch(void* const* d_in, const int* in_sizes, int n_in,
                              void* d_out, int out_size, void* d_ws, size_t ws_size,
                              hipStream_t stream) {
    const int*   x      = (const int*)d_in[0];     // (64, 1024)
    const int*   T      = (const int*)d_in[1];     // (64,)
    const float* priors = (const float*)d_in[2];   // (512,)
    const float* trans  = (const float*)d_in[3];   // (512, 512)
    const float* emit   = (const float*)d_in[4];   // (512, 10000)
    float* out = (float*)d_out;                    // (64, 1)

    char* ws = (char*)d_ws;
    u16*   Eb     = (u16*)(ws + WS_EB);
    u16*   Gb     = (u16*)(ws + WS_GB);
    u32*   A8     = (u32*)(ws + WS_A8);
    float* rowLSE = (float*)(ws + WS_ROWLSE);
    float* colLSE = (float*)(ws + WS_COLLSE);
    float* pinorm = (float*)(ws + WS_PINORM);

    k_row_lse<<<N_ST, 256, 0, stream>>>(emit, rowLSE);
    {
        dim3 g((VOCAB + 63) / 64, N_ST / 64);
        k_expEmitT<<<g, 256, 0, stream>>>(emit, rowLSE, Eb);
    }
    k_col_lse<<<N_ST, 256, 0, stream>>>(trans, colLSE);
    k_packA_fp8<<<128, 64, 0, stream>>>(trans, colLSE, A8);
    k_pinorm<<<1, 512, 0, stream>>>(priors, pinorm);
    k_G<<<VOCAB / 16, 256, 0, stream>>>(Eb, trans, colLSE, Gb);

    hmm_main<<<BATCH, 512, 0, stream>>>(x, T, Eb, A8, Gb, pinorm, out);
}

// Round 14
// 1227.627 us; speedup vs baseline: 2.3937x; 1.0416x over previous
//
#include <hip/hip_runtime.h>
#include <hip/hip_bf16.h>

// HMM forward on MI355X — K=128 MX-fp8 MFMA (unit scales), register-resident A,
// 1-step register prefetch of E/G rows, G-dot current-S normalization (exact
// telescope), RAW s_barrier (lgkm-only drain). hmm_main identical to the
// proven r8 kernel (1147 us, absmax 0.5). This round: k_G replaced by an
// MFMA GEMM (k_packAb + k_G_mfma) — G errors cancel exactly in the telescope,
// so bf16 MFMA G is risk-free.

typedef unsigned long long u64;
typedef unsigned int u32;
typedef unsigned short u16;
using f32x4 = __attribute__((ext_vector_type(4))) float;
using i32x8 = __attribute__((ext_vector_type(8))) int;
using short8 = __attribute__((ext_vector_type(8))) short;

#define N_ST 512
#define VOCAB 10000
#define BATCH 64
#define T_MAX 1024

// ---------------- workspace layout (bytes) ----------------
#define WS_EB       0          // E bf16: 10000*512*2 = 10,240,000
#define WS_GB       10240000   // G bf16: 10,240,000
#define WS_A8       20480000   // 128 frags * 2048 B = 262,144
#define WS_ABP      20742144   // Ab B-frag pack bf16: 512 frags * 1024 B = 524,288
#define WS_ROWLSE   21266432   // 512 f32
#define WS_COLLSE   21268480   // 512 f32
#define WS_PINORM   21270528   // 512 f32
// total 21,272,576 bytes

// ---- bf16 helpers ----
static __device__ __forceinline__ float bf16f(u16 h) {
    return __uint_as_float((u32)h << 16);
}
static __device__ __forceinline__ u16 bf16enc(float f) {
    u32 u = __float_as_uint(f);
    return (u16)((u + 0x7fffu + ((u >> 16) & 1u)) >> 16);
}

// ---- positive OCP e4m3fn decode ----
static __device__ __forceinline__ float dec8(u32 b) {
    float nrm = __uint_as_float((b << 20) + 0x3C000000u);
    float dnm = (float)b * 0x1p-9f;
    return b >= 8u ? nrm : dnm;
}

// ---- software e4m3fn encoder (fallback only) ----
static __device__ __forceinline__ u32 enc_e4m3(float f) {
    if (!(f > 0.f)) return 0u;
    unsigned u = __float_as_uint(f);
    int e = (int)((u >> 23) & 0xff) - 127;
    unsigned m = u & 0x7fffffu;
    if (e > 8 || (e == 8 && m >= 0x700000u)) return 0x7eu;
    if (e >= -6) {
        unsigned mant = m >> 20;
        unsigned rest = m & 0xfffffu;
        if (rest > 0x80000u || (rest == 0x80000u && (mant & 1u))) mant++;
        unsigned r = ((unsigned)(e + 7) << 3) + mant;
        return r > 0x7eu ? 0x7eu : r;
    }
    if (e < -10) return 0u;
    unsigned full = 0x800000u | m;
    int shift = 23 - (e + 9);
    unsigned r = full >> shift;
    unsigned rem = full & ((1u << shift) - 1u);
    unsigned half = 1u << (shift - 1);
    if (rem > half || (rem == half && (r & 1u))) r++;
    return r;
}

template <bool HI>
static __device__ __forceinline__ u32 cvtpk2(float a, float b, u32 old) {
#if __has_builtin(__builtin_amdgcn_cvt_pk_fp8_f32)
    return (u32)__builtin_amdgcn_cvt_pk_fp8_f32(a, b, (int)old, HI);
#else
    unsigned v = enc_e4m3(a) | (enc_e4m3(b) << 8);
    return HI ? ((old & 0x0000ffffu) | (v << 16)) : ((old & 0xffff0000u) | v);
#endif
}

// ---- rowLSE[n] = logsumexp_m emit[n, m] ----
__global__ __launch_bounds__(256) void k_row_lse(const float* __restrict__ emit,
                                                 float* __restrict__ rowLSE) {
    const int n = blockIdx.x;
    const float* row = emit + (size_t)n * VOCAB;
    __shared__ float redm[4], reds[4];
    const int tid = threadIdx.x, lane = tid & 63, wid = tid >> 6;

    float m = -INFINITY;
    for (int i = tid; i < VOCAB; i += 256) m = fmaxf(m, row[i]);
    #pragma unroll
    for (int o = 32; o; o >>= 1) m = fmaxf(m, __shfl_down(m, o));
    if (lane == 0) redm[wid] = m;
    __syncthreads();
    if (tid == 0) redm[0] = fmaxf(fmaxf(redm[0], redm[1]), fmaxf(redm[2], redm[3]));
    __syncthreads();
    m = redm[0];

    float s = 0.f;
    for (int i = tid; i < VOCAB; i += 256) s += __expf(row[i] - m);
    #pragma unroll
    for (int o = 32; o; o >>= 1) s += __shfl_down(s, o);
    if (lane == 0) reds[wid] = s;
    __syncthreads();
    if (tid == 0) rowLSE[n] = m + __logf(reds[0] + reds[1] + reds[2] + reds[3]);
}

// ---- Eb[m*512+n] = bf16( exp(emit[n,m] - rowLSE[n]) ), tiled transpose ----
__global__ __launch_bounds__(256) void k_expEmitT(const float* __restrict__ emit,
                                                  const float* __restrict__ rowLSE,
                                                  u16* __restrict__ Eb) {
    __shared__ float tile[64][65];
    const int m0 = blockIdx.x * 64;
    const int n0 = blockIdx.y * 64;
    const int tid = threadIdx.x;

    #pragma unroll
    for (int it = 0; it < 16; ++it) {
        const int idx = it * 256 + tid;
        const int mm = idx & 63, nn = idx >> 6;
        const int m = m0 + mm;
        tile[nn][mm] = (m < VOCAB) ? emit[(size_t)(n0 + nn) * VOCAB + m] : 0.f;
    }
    __syncthreads();
    #pragma unroll
    for (int it = 0; it < 16; ++it) {
        const int idx = it * 256 + tid;
        const int nn = idx & 63, mm = idx >> 6;
        const int m = m0 + mm;
        if (m < VOCAB)
            Eb[(size_t)m * N_ST + n0 + nn] =
                bf16enc(__expf(tile[nn][mm] - rowLSE[n0 + nn]));
    }
}

// ---- colLSE[k] = logsumexp_j trans[j, k] ----
__global__ __launch_bounds__(256) void k_col_lse(const float* __restrict__ trans,
                                                 float* __restrict__ colLSE) {
    const int k = blockIdx.x;
    const int tid = threadIdx.x, lane = tid & 63, wid = tid >> 6;
    __shared__ float redm[4], reds[4];

    float a = trans[(size_t)tid * N_ST + k];
    float b = trans[(size_t)(tid + 256) * N_ST + k];
    float m = fmaxf(a, b);
    #pragma unroll
    for (int o = 32; o; o >>= 1) m = fmaxf(m, __shfl_down(m, o));
    if (lane == 0) redm[wid] = m;
    __syncthreads();
    if (tid == 0) redm[0] = fmaxf(fmaxf(redm[0], redm[1]), fmaxf(redm[2], redm[3]));
    __syncthreads();
    m = redm[0];

    float s = __expf(a - m) + __expf(b - m);
    #pragma unroll
    for (int o = 32; o; o >>= 1) s += __shfl_down(s, o);
    if (lane == 0) reds[wid] = s;
    __syncthreads();
    if (tid == 0) colLSE[k] = m + __logf(reds[0] + reds[1] + reds[2] + reds[3]);
}

// ---- pack A (column-softmax of trans, x256) into fp8 K=128 MFMA A-fragments ----
__global__ __launch_bounds__(64) void k_packA_fp8(const float* __restrict__ trans,
                                                  const float* __restrict__ colLSE,
                                                  u32* __restrict__ A8) {
    const int f = blockIdx.x;        // 0..127
    const int l = threadIdx.x;       // 0..63
    const int w = f >> 4, ks = (f >> 2) & 3, jt = f & 3;
    const int j = w * 64 + jt * 16 + (l & 15);
    const int k0 = ks * 128 + (l >> 4) * 32;
    u32 dw[8];
    #pragma unroll
    for (int d = 0; d < 8; ++d) {
        float a0 = 256.0f * __expf(trans[(size_t)j * N_ST + k0 + 4 * d + 0] - colLSE[k0 + 4 * d + 0]);
        float a1 = 256.0f * __expf(trans[(size_t)j * N_ST + k0 + 4 * d + 1] - colLSE[k0 + 4 * d + 1]);
        float a2 = 256.0f * __expf(trans[(size_t)j * N_ST + k0 + 4 * d + 2] - colLSE[k0 + 4 * d + 2]);
        float a3 = 256.0f * __expf(trans[(size_t)j * N_ST + k0 + 4 * d + 3] - colLSE[k0 + 4 * d + 3]);
        u32 pk = cvtpk2<false>(a0, a1, 0u);
        dw[d] = cvtpk2<true>(a2, a3, pk);
    }
    u32* dst = A8 + (size_t)f * 512 + l * 8;
    *(uint4*)dst       = make_uint4(dw[0], dw[1], dw[2], dw[3]);
    *(uint4*)(dst + 4) = make_uint4(dw[4], dw[5], dw[6], dw[7]);
}

// ---- pinorm[j] = softmax(priors)[j] ----
__global__ __launch_bounds__(512) void k_pinorm(const float* __restrict__ priors,
                                                float* __restrict__ pinorm) {
    const int j = threadIdx.x, lane = j & 63, wid = j >> 6;
    __shared__ float redm[8], reds[8];
    float v = priors[j];

    float m = v;
    #pragma unroll
    for (int o = 32; o; o >>= 1) m = fmaxf(m, __shfl_down(m, o));
    if (lane == 0) redm[wid] = m;
    __syncthreads();
    if (j == 0) {
        float r = redm[0];
        for (int i = 1; i < 8; ++i) r = fmaxf(r, redm[i]);
        redm[0] = r;
    }
    __syncthreads();
    m = redm[0];

    float s = __expf(v - m);
    #pragma unroll
    for (int o = 32; o; o >>= 1) s += __shfl_down(s, o);
    if (lane == 0) reds[wid] = s;
    __syncthreads();
    if (j == 0) {
        float r = 0.f;
        for (int i = 0; i < 8; ++i) r += reds[i];
        reds[0] = r;
    }
    __syncthreads();
    pinorm[j] = __expf(v - m) / reds[0];
}

// ---- pack Ab (plain exp(trans-colLSE), bf16) into 16x16x32 B-fragments ----
// frag f = nt*16 + js (nt = k-tile of 16, js = j-slice of 32);
// lane l, elem i: Ab[j][k], j = js*32 + (l>>4)*8 + i, k = nt*16 + (l&15)
__global__ __launch_bounds__(64) void k_packAb(const float* __restrict__ trans,
                                               const float* __restrict__ colLSE,
                                               u16* __restrict__ Abp) {
    const int f = blockIdx.x;        // 0..511
    const int l = threadIdx.x;
    const int nt = f >> 4, js = f & 15;
    const int k = nt * 16 + (l & 15);
    const int j0 = js * 32 + (l >> 4) * 8;
    const float c = colLSE[k];
    short8 v;
    #pragma unroll
    for (int i = 0; i < 8; ++i)
        v[i] = (short)bf16enc(__expf(trans[(size_t)(j0 + i) * N_ST + k] - c));
    *(short8*)(Abp + (size_t)f * 512 + l * 8) = v;
}

// ---- G[m][k] = sum_j E[m][j]*Ab[j][k] via bf16 MFMA; one wave per 16-row strip ----
// A-frag: lane l holds E[m0+(l&15)][js*32+(l>>4)*8+i] (16B contiguous in Eb).
// D-frag: col = l&15, row = (l>>4)*4 + r.
__global__ __launch_bounds__(64) void k_G_mfma(const u16* __restrict__ Eb,
                                               const u16* __restrict__ Abp,
                                               u16* __restrict__ Gb) {
    const int mt = blockIdx.x;       // 0..624
    const int l = threadIdx.x;
    const int m0 = mt * 16;
    const int row = (l >> 4) * 4;
    const int col = l & 15;

    short8 ef[16];
    #pragma unroll
    for (int js = 0; js < 16; ++js)
        ef[js] = *(const short8*)(Eb + (size_t)(m0 + (l & 15)) * N_ST + js * 32 + (l >> 4) * 8);

    for (int nt = 0; nt < 32; ++nt) {
        f32x4 acc = {0.f, 0.f, 0.f, 0.f};
        #pragma unroll
        for (int js = 0; js < 16; ++js) {
            const short8 bf = *(const short8*)(Abp + (size_t)(nt * 16 + js) * 512 + l * 8);
            acc = __builtin_amdgcn_mfma_f32_16x16x32_bf16(ef[js], bf, acc, 0, 0, 0);
        }
        #pragma unroll
        for (int r = 0; r < 4; ++r)
            Gb[(size_t)(m0 + row + r) * N_ST + nt * 16 + col] = bf16enc(acc[r]);
    }
}

#define UNIT_SCALES 0x7f7f7f7f   // 4x e8m0 "1.0"
#define LN256 5.545177444479562f

// raw workgroup barrier: drain LDS only (vmem prefetch stays in flight)
#define WG_BARRIER()                                        \
  {                                                         \
    asm volatile("s_waitcnt lgkmcnt(0)" ::: "memory");      \
    __builtin_amdgcn_s_barrier();                           \
    asm volatile("" ::: "memory");                          \
  }

// one HMM step; EU/GU = current-step E/G regs, EP/GP = prefetch targets
#define STEP_BODY(EU, GU, EP, GP)                                               \
  {                                                                             \
    const int xpre = xnext;                                                     \
    GP = *(const uint4*)((const char*)Gb + ((size_t)xpre << 10) + (l << 4));    \
    _Pragma("unroll")                                                           \
    for (int jt = 0; jt < 4; ++jt)                                              \
      EP[jt] = *(const u64*)(Eb + (size_t)xpre * N_ST + wbase + jt * 16 + rbase); \
    xnext = xb[(t + 2 <= Tf) ? (t + 2) : Tf];                                   \
    const u64 vown = vq[p][l];                                                  \
    const u32* vbase = (const u32*)&vq[p][0];                                   \
    i32x8 bq[4];                                                                \
    _Pragma("unroll")                                                           \
    for (int ks = 0; ks < 4; ++ks) {                                            \
      const uint4 b0 = *(const uint4*)(vbase + ks * 32 + grp * 8);              \
      const uint4 b1 = *(const uint4*)(vbase + ks * 32 + grp * 8 + 4);          \
      bq[ks] = i32x8{(int)b0.x, (int)b0.y, (int)b0.z, (int)b0.w,                \
                     (int)b1.x, (int)b1.y, (int)b1.z, (int)b1.w};               \
    }                                                                           \
    f32x4 aA0={0,0,0,0}, aA1={0,0,0,0}, aA2={0,0,0,0}, aA3={0,0,0,0};           \
    f32x4 aB0={0,0,0,0}, aB1={0,0,0,0}, aB2={0,0,0,0}, aB3={0,0,0,0};           \
    _Pragma("unroll")                                                           \
    for (int kk = 0; kk < 2; ++kk) {                                            \
      const int ksA = kk * 2, ksB = kk * 2 + 1;                                 \
      aA0 = __builtin_amdgcn_mfma_scale_f32_16x16x128_f8f6f4(                   \
                af[ksA * 4 + 0], bq[ksA], aA0, 0, 0, 0, UNIT_SCALES, 0, UNIT_SCALES); \
      aB0 = __builtin_amdgcn_mfma_scale_f32_16x16x128_f8f6f4(                   \
                af[ksB * 4 + 0], bq[ksB], aB0, 0, 0, 0, UNIT_SCALES, 0, UNIT_SCALES); \
      aA1 = __builtin_amdgcn_mfma_scale_f32_16x16x128_f8f6f4(                   \
                af[ksA * 4 + 1], bq[ksA], aA1, 0, 0, 0, UNIT_SCALES, 0, UNIT_SCALES); \
      aB1 = __builtin_amdgcn_mfma_scale_f32_16x16x128_f8f6f4(                   \
                af[ksB * 4 + 1], bq[ksB], aB1, 0, 0, 0, UNIT_SCALES, 0, UNIT_SCALES); \
      aA2 = __builtin_amdgcn_mfma_scale_f32_16x16x128_f8f6f4(                   \
                af[ksA * 4 + 2], bq[ksA], aA2, 0, 0, 0, UNIT_SCALES, 0, UNIT_SCALES); \
      aB2 = __builtin_amdgcn_mfma_scale_f32_16x16x128_f8f6f4(                   \
                af[ksB * 4 + 2], bq[ksB], aB2, 0, 0, 0, UNIT_SCALES, 0, UNIT_SCALES); \
      aA3 = __builtin_amdgcn_mfma_scale_f32_16x16x128_f8f6f4(                   \
                af[ksA * 4 + 3], bq[ksA], aA3, 0, 0, 0, UNIT_SCALES, 0, UNIT_SCALES); \
      aB3 = __builtin_amdgcn_mfma_scale_f32_16x16x128_f8f6f4(                   \
                af[ksB * 4 + 3], bq[ksB], aB3, 0, 0, 0, UNIT_SCALES, 0, UNIT_SCALES); \
    }                                                                           \
    float gv = 0.f;                                                             \
    {                                                                           \
      const u32 gw[4] = {GU.x, GU.y, GU.z, GU.w};                               \
      _Pragma("unroll")                                                         \
      for (int i = 0; i < 4; ++i) {                                             \
        float g0 = bf16f((u16)(gw[i] & 0xffffu));                               \
        float g1 = bf16f((u16)(gw[i] >> 16));                                   \
        float v0 = dec8((u32)(vown >> (16 * i)) & 0xffu);                       \
        float v1 = dec8((u32)(vown >> (16 * i + 8)) & 0xffu);                   \
        gv = fmaf(g0, v0, gv);                                                  \
        gv = fmaf(g1, v1, gv);                                                  \
      }                                                                         \
      _Pragma("unroll")                                                         \
      for (int o = 1; o <= 32; o <<= 1) gv += __shfl_xor(gv, o);                \
    }                                                                           \
    float wv2[16];                                                              \
    _Pragma("unroll")                                                           \
    for (int r = 0; r < 4; ++r) {                                               \
      wv2[0 + r]  = bf16f((u16)(EU[0] >> (16 * r))) * (aA0[r] + aB0[r]);        \
      wv2[4 + r]  = bf16f((u16)(EU[1] >> (16 * r))) * (aA1[r] + aB1[r]);        \
      wv2[8 + r]  = bf16f((u16)(EU[2] >> (16 * r))) * (aA2[r] + aB2[r]);        \
      wv2[12 + r] = bf16f((u16)(EU[3] >> (16 * r))) * (aA3[r] + aB3[r]);        \
    }                                                                           \
    if (t == Tf) {                                                              \
      float s2 = 0.f;                                                           \
      _Pragma("unroll")                                                         \
      for (int i = 0; i < 16; ++i) s2 += wv2[i];                                \
      s2 += __shfl_xor(s2, 16);                                                 \
      s2 += __shfl_xor(s2, 32);                                                 \
      if (l == 0) red[wid] = s2;                                                \
      __syncthreads();                                                          \
      const float Se = red[0] + red[1] + red[2] + red[3] +                      \
                       red[4] + red[5] + red[6] + red[7];                       \
      if (tid == 0) out[b] = L + __logf(Se) - (float)Tb * LN256;                \
    } else {                                                                    \
      L += __logf(gv);                                                          \
      const float sc = 1.0f / gv;                                               \
      if ((l & 15) == 0) {                                                      \
        u32* vw = (u32*)&vq[p ^ 1][0];                                          \
        _Pragma("unroll")                                                       \
        for (int jt = 0; jt < 4; ++jt) {                                        \
          u32 pk = cvtpk2<false>(wv2[jt * 4 + 0] * sc, wv2[jt * 4 + 1] * sc, 0u); \
          pk = cvtpk2<true>(wv2[jt * 4 + 2] * sc, wv2[jt * 4 + 3] * sc, pk);    \
          vw[(wbase >> 2) + jt * 4 + grp] = pk;                                 \
        }                                                                       \
      }                                                                         \
      WG_BARRIER();                                                             \
      p ^= 1;                                                                   \
    }                                                                           \
  }

// ---- main: one WG per chain; 8 waves x 64 states; A resident (K=128 frags) ----
__global__ __launch_bounds__(512, 2) void hmm_main(const int* __restrict__ x,
                                                   const int* __restrict__ T,
                                                   const u16* __restrict__ Eb,
                                                   const u32* __restrict__ A8,
                                                   const u16* __restrict__ Gb,
                                                   const float* __restrict__ pinorm,
                                                   float* __restrict__ out) {
    __shared__ u64 vq[2][64];
    __shared__ float red[8];
    const int b = blockIdx.x;
    const int tid = threadIdx.x;
    const int l = tid & 63;
    const int wid = tid >> 6;
    const int grp = l >> 4;
    const int wbase = wid * 64;
    const int rbase = grp * 4;

    int Tb = T[b];
    Tb = Tb < 1 ? 1 : (Tb > T_MAX ? T_MAX : Tb);
    const int* xb = x + (size_t)b * T_MAX;

    // resident A fragments: 16 x 32 B per lane (128 VGPRs)
    i32x8 af[16];
    {
        const u32* ap = A8 + (size_t)wid * 16 * 512 + l * 8;
        #pragma unroll
        for (int i = 0; i < 16; ++i) {
            uint4 lo = *(const uint4*)(ap + (size_t)i * 512);
            uint4 hi = *(const uint4*)(ap + (size_t)i * 512 + 4);
            af[i] = i32x8{(int)lo.x, (int)lo.y, (int)lo.z, (int)lo.w,
                          (int)hi.x, (int)hi.y, (int)hi.z, (int)hi.w};
        }
    }

    // prefetch E/G for t=1 immediately (x known upfront; harmless if Tb==1)
    const int x0 = xb[0];
    const int x1 = xb[1];
    u64 eA[4], eB[4];
    uint4 gA, gB;
    gA = *(const uint4*)((const char*)Gb + ((size_t)x1 << 10) + (l << 4));
    #pragma unroll
    for (int jt = 0; jt < 4; ++jt)
        eA[jt] = *(const u64*)(Eb + (size_t)x1 * N_ST + wbase + jt * 16 + rbase);

    // ---- t = 0 ----
    float wv[16];
    float s = 0.f;
    #pragma unroll
    for (int jt = 0; jt < 4; ++jt) {
        u64 eraw = *(const u64*)(Eb + (size_t)x0 * N_ST + wbase + jt * 16 + rbase);
        #pragma unroll
        for (int r = 0; r < 4; ++r) {
            const int j = wbase + jt * 16 + rbase + r;
            float e = bf16f((u16)(eraw >> (16 * r)));
            float t0 = e * pinorm[j];
            wv[jt * 4 + r] = t0;
            s += t0;
        }
    }
    s += __shfl_xor(s, 16);
    s += __shfl_xor(s, 32);
    if (l == 0) red[wid] = s;
    __syncthreads();
    float S0 = red[0] + red[1] + red[2] + red[3] + red[4] + red[5] + red[6] + red[7];
    float L = __logf(S0);
    if (Tb == 1) {
        if (tid == 0) out[b] = L;
        return;
    }
    __syncthreads();
    {
        const float sc = 256.0f / S0;
        if ((l & 15) == 0) {
            u32* vw = (u32*)&vq[0][0];
            #pragma unroll
            for (int jt = 0; jt < 4; ++jt) {
                u32 pk = cvtpk2<false>(wv[jt * 4 + 0] * sc, wv[jt * 4 + 1] * sc, 0u);
                pk = cvtpk2<true>(wv[jt * 4 + 2] * sc, wv[jt * 4 + 3] * sc, pk);
                vw[(wbase >> 2) + jt * 4 + grp] = pk;
            }
        }
    }
    __syncthreads();

    // ---- t = 1 .. Tb-1 (unroll-2 with register E/G double-buffer) ----
    const int Tf = Tb - 1;
    int p = 0;
    int xnext = xb[(2 <= Tf) ? 2 : Tf];
    for (int t = 1;;) {
        STEP_BODY(eA, gA, eB, gB)
        if (t == Tf) break;
        ++t;
        STEP_BODY(eB, gB, eA, gA)
        if (t == Tf) break;
        ++t;
    }
}

extern "C" void kernel_launch(void* const* d_in, const int* in_sizes, int n_in,
                              void* d_out, int out_size, void* d_ws, size_t ws_size,
                              hipStream_t stream) {
    const int*   x      = (const int*)d_in[0];     // (64, 1024)
    const int*   T      = (const int*)d_in[1];     // (64,)
    const float* priors = (const float*)d_in[2];   // (512,)
    const float* trans  = (const float*)d_in[3];   // (512, 512)
    const float* emit   = (const float*)d_in[4];   // (512, 10000)
    float* out = (float*)d_out;                    // (64, 1)

    char* ws = (char*)d_ws;
    u16*   Eb     = (u16*)(ws + WS_EB);
    u16*   Gb     = (u16*)(ws + WS_GB);
    u32*   A8     = (u32*)(ws + WS_A8);
    u16*   Abp    = (u16*)(ws + WS_ABP);
    float* rowLSE = (float*)(ws + WS_ROWLSE);
    float* colLSE = (float*)(ws + WS_COLLSE);
    float* pinorm = (float*)(ws + WS_PINORM);

    k_row_lse<<<N_ST, 256, 0, stream>>>(emit, rowLSE);
    {
        dim3 g((VOCAB + 63) / 64, N_ST / 64);
        k_expEmitT<<<g, 256, 0, stream>>>(emit, rowLSE, Eb);
    }
    k_col_lse<<<N_ST, 256, 0, stream>>>(trans, colLSE);
    k_packA_fp8<<<128, 64, 0, stream>>>(trans, colLSE, A8);
    k_pinorm<<<1, 512, 0, stream>>>(priors, pinorm);
    k_packAb<<<512, 64, 0, stream>>>(trans, colLSE, Abp);
    k_G_mfma<<<VOCAB / 16, 64, 0, stream>>>(Eb, Abp, Gb);

    hmm_main<<<BATCH, 512, 0, stream>>>(x, T, Eb, A8, Gb, pinorm, out);
}